// Round 8
// baseline (425.706 us; speedup 1.0000x reference)
//
#include <hip/hip_runtime.h>
#include <hip/hip_bf16.h>

// GCNBlock: 9-dispatch pipeline; h' stored bf16 column-sliced (8 x 3.2MB) for
// per-XCD L2-resident gathers. N=50000, E=800000, F=256

#define F 256
#define EPSV 1e-5f

typedef __attribute__((ext_vector_type(8))) short short8;
typedef __attribute__((ext_vector_type(4))) float f32x4;
typedef __attribute__((ext_vector_type(4))) unsigned short us4;

__device__ __forceinline__ unsigned short f2bf(float f) {
  union { float f; unsigned u; } v; v.f = f;
  unsigned r = v.u + 0x7fffu + ((v.u >> 16) & 1u);  // RNE
  return (unsigned short)(r >> 16);
}

__device__ __forceinline__ float bf2f(unsigned short u) {
  union { unsigned u; float f; } v; v.u = ((unsigned)u) << 16; return v.f;
}

// ---- count + rank (edges) ; prep_W (blocks >= eb) --------------------------

__global__ void count_rank(const int* __restrict__ dst, int* __restrict__ deg_cnt,
                           int* __restrict__ rank, int E, int eb,
                           const float* __restrict__ W, unsigned short* __restrict__ Wb) {
  if ((int)blockIdx.x < eb) {
    int e = blockIdx.x * 256 + threadIdx.x;
    if (e < E) rank[e] = atomicAdd(&deg_cnt[dst[e]], 1);
    return;
  }
  int gid = (blockIdx.x - eb) * 256 + threadIdx.x;  // 65536 total
  int j = gid & 7;
  int lane = (gid >> 3) & 63;
  int kc = (gid >> 9) & 7;
  int tt = gid >> 12;
  int k = kc * 32 + (lane >> 4) * 8 + j;
  int n = tt * 16 + (lane & 15);
  Wb[gid] = f2bf(W[k * 256 + n]);
}

// ---- parallel scan chain ---------------------------------------------------

__global__ void block_sums(const int* __restrict__ deg_cnt, int* __restrict__ bsum,
                           float* __restrict__ dinv, int N) {
  __shared__ int s[256];
  int t = threadIdx.x;
  int i = blockIdx.x * 256 + t;
  int d = (i < N) ? deg_cnt[i] : 0;
  if (i < N) dinv[i] = rsqrtf((float)(d + 1));  // +1 self loop
  s[t] = d;
  __syncthreads();
  for (int off = 128; off > 0; off >>= 1) {
    if (t < off) s[t] += s[t + off];
    __syncthreads();
  }
  if (t == 0) bsum[blockIdx.x] = s[0];
}

__global__ void scan_bsums(const int* __restrict__ bsum, int* __restrict__ boff, int nb) {
  __shared__ int s[256];
  int t = threadIdx.x;
  int v = (t < nb) ? bsum[t] : 0;
  s[t] = v;
  __syncthreads();
  for (int off = 1; off < 256; off <<= 1) {
    int x = (t >= off) ? s[t - off] : 0;
    __syncthreads();
    s[t] += x;
    __syncthreads();
  }
  if (t < nb) boff[t] = s[t] - v;  // exclusive
}

__global__ void write_csr(const int* __restrict__ deg_cnt, const int* __restrict__ boff,
                          int* __restrict__ csr_ptr, int N, int E) {
  __shared__ int s[256];
  int t = threadIdx.x;
  int i = blockIdx.x * 256 + t;
  int v = (i < N) ? deg_cnt[i] : 0;
  s[t] = v;
  __syncthreads();
  for (int off = 1; off < 256; off <<= 1) {
    int x = (t >= off) ? s[t - off] : 0;
    __syncthreads();
    s[t] += x;
    __syncthreads();
  }
  if (i < N) csr_ptr[i] = boff[blockIdx.x] + s[t] - v;
  if (i == 0) csr_ptr[N] = E;
}

// ---- fill (atomic-free, blocks < eb) ; gemm (blocks >= eb) -----------------
// gemm writes h' bf16 into slice-major hbs[s][row][8 x us4]

__global__ void fill_gemm(const int* __restrict__ src, const int* __restrict__ dst,
                          const int* __restrict__ rank, const int* __restrict__ csr_ptr,
                          int* __restrict__ csr_src, int E, int eb,
                          const float* __restrict__ x, const unsigned short* __restrict__ Wb,
                          const float* __restrict__ dinv, us4* __restrict__ hbs, int N) {
  __shared__ unsigned short lds[16][264];  // gemm repack; +8 pad breaks bank alias

  if ((int)blockIdx.x < eb) {
    int e = blockIdx.x * 256 + threadIdx.x;
    if (e < E) {
      int d = dst[e];
      csr_src[csr_ptr[d] + rank[e]] = src[e];
    }
    return;
  }

  int bid = blockIdx.x - eb;
  int lane = threadIdx.x & 63;
  int wave = threadIdx.x >> 6;
  int m0 = bid * 16;
  int q = lane >> 4;

  int row = m0 + (lane & 15);
  int rowc = row < N ? row : N - 1;

  f32x4 acc[4] = {{0,0,0,0},{0,0,0,0},{0,0,0,0},{0,0,0,0}};

  for (int kc = 0; kc < 8; ++kc) {
    int koff = kc * 32 + q * 8;
    const float4* xp = (const float4*)(x + (size_t)rowc * F + koff);
    float4 a0 = xp[0];
    float4 a1 = xp[1];
    short8 a;
    a[0] = f2bf(a0.x); a[1] = f2bf(a0.y); a[2] = f2bf(a0.z); a[3] = f2bf(a0.w);
    a[4] = f2bf(a1.x); a[5] = f2bf(a1.y); a[6] = f2bf(a1.z); a[7] = f2bf(a1.w);
#pragma unroll
    for (int tt = 0; tt < 4; ++tt) {
      const short8 b = *(const short8*)(Wb + (((wave * 4 + tt) * 8 + kc) * 64 + lane) * 8);
      acc[tt] = __builtin_amdgcn_mfma_f32_16x16x32_bf16(a, b, acc[tt], 0, 0, 0);
    }
  }

  int crow = q * 4;
  int ccol = lane & 15;
#pragma unroll
  for (int rr = 0; rr < 4; ++rr) {
    int orow = m0 + crow + rr;
    float dv = (orow < N) ? dinv[orow] : 0.f;
#pragma unroll
    for (int tt = 0; tt < 4; ++tt) {
      lds[crow + rr][wave * 64 + tt * 16 + ccol] = f2bf(acc[tt][rr] * dv);
    }
  }
  __syncthreads();
  int t = threadIdx.x;
  int lrow = t >> 4;
  int grow = m0 + lrow;
  if (grow < N) {
#pragma unroll
    for (int it = 0; it < 4; ++it) {
      int c4 = (t & 15) + 16 * it;  // us4 index 0..63 over 256 cols
      us4 u = *(const us4*)&lds[lrow][c4 * 4];
      int sl = c4 >> 3, cc = c4 & 7;
      __builtin_nontemporal_store(u, &hbs[((size_t)sl * N + grow) * 8 + cc]);
    }
  }
}

// ---- Aggregation: slice-per-XCD gather -------------------------------------
// blockIdx%8 = column slice (32 cols, 3.2MB table -> fits one XCD L2).
// Wave handles one dst row: lanes = 8 edges x 8 col-chunks (us4).

__global__ void aggregate(const us4* __restrict__ hbs, const int* __restrict__ csr_ptr,
                          const int* __restrict__ csr_src, const float* __restrict__ dinv,
                          const float4* __restrict__ conv_bias4, f32x4* __restrict__ out4,
                          float2* __restrict__ partials, int N) {
  int sl = blockIdx.x & 7;
  int rb = blockIdx.x >> 3;
  int wave = threadIdx.x >> 6;
  int lane = threadIdx.x & 63;
  int j = lane >> 3;   // edge slot 0..7
  int c = lane & 7;    // col chunk 0..7 (us4)
  int row = rb * 4 + wave;
  float ps1 = 0.f, ps2 = 0.f;

  if (row < N) {
    const us4* tab = hbs + (size_t)sl * N * 8;
    int b0 = csr_ptr[row], b1 = csr_ptr[row + 1];
    float ax = 0.f, ay = 0.f, az = 0.f, aw = 0.f;

    for (int e = b0; e < b1; e += 16) {
      int e0 = e + j, e1 = e + 8 + j;
      int i0 = __builtin_nontemporal_load(csr_src + (e0 < b1 ? e0 : b1 - 1));
      int i1 = __builtin_nontemporal_load(csr_src + (e1 < b1 ? e1 : b1 - 1));
      us4 v0 = tab[(size_t)i0 * 8 + c];
      us4 v1 = tab[(size_t)i1 * 8 + c];
      float m0 = (e0 < b1) ? 1.f : 0.f;
      float m1 = (e1 < b1) ? 1.f : 0.f;
      ax = fmaf(bf2f(v0.x), m0, ax); ay = fmaf(bf2f(v0.y), m0, ay);
      az = fmaf(bf2f(v0.z), m0, az); aw = fmaf(bf2f(v0.w), m0, aw);
      ax = fmaf(bf2f(v1.x), m1, ax); ay = fmaf(bf2f(v1.y), m1, ay);
      az = fmaf(bf2f(v1.z), m1, az); aw = fmaf(bf2f(v1.w), m1, aw);
    }

    // butterfly-reduce across the 8 edge slots (lane bits 3..5)
#pragma unroll
    for (int off = 8; off <= 32; off <<= 1) {
      ax += __shfl_xor(ax, off, 64);
      ay += __shfl_xor(ay, off, 64);
      az += __shfl_xor(az, off, 64);
      aw += __shfl_xor(aw, off, 64);
    }

    // self loop + scale + bias (all lanes compute; slot 0 stores)
    us4 sv = tab[(size_t)row * 8 + c];
    ax += bf2f(sv.x); ay += bf2f(sv.y); az += bf2f(sv.z); aw += bf2f(sv.w);
    float di = dinv[row];
    float4 b = conv_bias4[sl * 8 + c];
    f32x4 y;
    y.x = fmaf(ax, di, b.x);
    y.y = fmaf(ay, di, b.y);
    y.z = fmaf(az, di, b.z);
    y.w = fmaf(aw, di, b.w);
    if (j == 0) {
      __builtin_nontemporal_store(y, &out4[(size_t)row * 64 + sl * 8 + c]);
      ps1 = y.x + y.y + y.z + y.w;
      ps2 = y.x * y.x + y.y * y.y + y.z * y.z + y.w * y.w;
    }
  }

  __shared__ float r1[256];
  __shared__ float r2[256];
  int t = threadIdx.x;
  r1[t] = ps1;
  r2[t] = ps2;
  __syncthreads();
  for (int off = 128; off > 0; off >>= 1) {
    if (t < off) { r1[t] += r1[t + off]; r2[t] += r2[t + off]; }
    __syncthreads();
  }
  if (t == 0) {
    float2 pp;
    pp.x = r1[0];
    pp.y = r2[0];
    partials[blockIdx.x] = pp;
  }
}

__global__ void finalize_stats(const float2* __restrict__ partials, int nb,
                               float* __restrict__ stats, double cnt) {
  __shared__ double q1[1024];
  __shared__ double q2[1024];
  int t = threadIdx.x;
  double a1 = 0.0, a2 = 0.0;
  for (int i = t; i < nb; i += 1024) {
    float2 pp = partials[i];
    a1 += (double)pp.x;
    a2 += (double)pp.y;
  }
  q1[t] = a1;
  q2[t] = a2;
  __syncthreads();
  for (int off = 512; off > 0; off >>= 1) {
    if (t < off) { q1[t] += q1[t + off]; q2[t] += q2[t + off]; }
    __syncthreads();
  }
  if (t == 0) {
    double mu = q1[0] / cnt;
    double var = q2[0] / cnt - mu * mu;
    if (var < 0) var = 0;
    double sd = sqrt(var);
    stats[0] = (float)mu;
    stats[1] = (float)(1.0 / (sd + (double)EPSV));
  }
}

__global__ void norm_prelu(float4* __restrict__ out, const float* __restrict__ stats,
                           const float* __restrict__ lw, const float* __restrict__ lb,
                           const float* __restrict__ pa, int n4) {
  int i = blockIdx.x * blockDim.x + threadIdx.x;
  if (i >= n4) return;
  float mu = stats[0];
  float inv = stats[1];
  float a = pa[0];
  int c4 = (i & 63) * 4;
  float4 w = *(const float4*)(lw + c4);
  float4 b = *(const float4*)(lb + c4);
  float4 v = out[i];
  float y0 = (v.x - mu) * inv * w.x + b.x;
  float y1 = (v.y - mu) * inv * w.y + b.y;
  float y2 = (v.z - mu) * inv * w.z + b.z;
  float y3 = (v.w - mu) * inv * w.w + b.w;
  v.x = y0 >= 0.f ? y0 : a * y0;
  v.y = y1 >= 0.f ? y1 : a * y1;
  v.z = y2 >= 0.f ? y2 : a * y2;
  v.w = y3 >= 0.f ? y3 : a * y3;
  out[i] = v;
}

// ---- launch ---------------------------------------------------------------

extern "C" void kernel_launch(void* const* d_in, const int* in_sizes, int n_in,
                              void* d_out, int out_size, void* d_ws, size_t ws_size,
                              hipStream_t stream) {
  const float* x = (const float*)d_in[0];
  const int* eidx = (const int*)d_in[1];
  const float* W = (const float*)d_in[3];
  const float* conv_bias = (const float*)d_in[4];
  const float* ln_w = (const float*)d_in[5];
  const float* ln_b = (const float*)d_in[6];
  const float* prelu_a = (const float*)d_in[7];
  float* out = (float*)d_out;

  int N = in_sizes[0] / F;
  int E = in_sizes[1] / 2;
  const int* src = eidx;
  const int* dst = eidx + E;

  int rowBlocks = (N + 3) / 4;
  int nAggBlocks = rowBlocks * 8;
  int eb = (E + 255) / 256;
  int gemmb = (N + 15) / 16;
  int NB = (N + 255) / 256;

  char* p = (char*)d_ws;
  auto carve = [&](size_t bytes) { char* r = p; p += (bytes + 255) & ~(size_t)255; return r; };
  us4* hbs       = (us4*)carve((size_t)N * 64 * sizeof(us4));  // sliced bf16 h'
  unsigned short* Wb = (unsigned short*)carve((size_t)F * F * sizeof(short));
  int* deg_cnt   = (int*)carve((size_t)N * sizeof(int));
  int* rank      = (int*)carve((size_t)E * sizeof(int));
  float* dinv    = (float*)carve((size_t)N * sizeof(float));
  int* csr_ptr   = (int*)carve((size_t)(N + 1) * sizeof(int));
  int* csr_src   = (int*)carve((size_t)E * sizeof(int));
  int* bsum      = (int*)carve((size_t)NB * sizeof(int));
  int* boff      = (int*)carve((size_t)NB * sizeof(int));
  float2* partials = (float2*)carve((size_t)nAggBlocks * sizeof(float2));
  float* stats   = (float*)carve(2 * sizeof(float));

  hipMemsetAsync(deg_cnt, 0, (size_t)N * sizeof(int), stream);

  count_rank<<<eb + 256, 256, 0, stream>>>(dst, deg_cnt, rank, E, eb, W, Wb);
  block_sums<<<NB, 256, 0, stream>>>(deg_cnt, bsum, dinv, N);
  scan_bsums<<<1, 256, 0, stream>>>(bsum, boff, NB);
  write_csr<<<NB, 256, 0, stream>>>(deg_cnt, boff, csr_ptr, N, E);
  fill_gemm<<<eb + gemmb, 256, 0, stream>>>(src, dst, rank, csr_ptr, csr_src, E, eb,
                                            x, Wb, dinv, hbs, N);
  aggregate<<<nAggBlocks, 256, 0, stream>>>(hbs, csr_ptr, csr_src, dinv,
                                            (const float4*)conv_bias, (f32x4*)out,
                                            partials, N);
  finalize_stats<<<1, 1024, 0, stream>>>(partials, nAggBlocks, stats,
                                         (double)N * (double)F);
  int n4 = N * (F / 4);
  norm_prelu<<<(n4 + 255) / 256, 256, 0, stream>>>((float4*)out, stats, ln_w, ln_b, prelu_a, n4);
}

// Round 9
// 333.623 us; speedup vs baseline: 1.2760x; 1.2760x over previous
//
#include <hip/hip_runtime.h>
#include <hip/hip_bf16.h>

// GCNBlock: 9-dispatch pipeline; h' bf16 column-sliced (8 x 3.2MB) for per-XCD
// L2-resident gathers; thread-owns-(row,chunk) aggregation with 8-deep MLP.
// N=50000, E=800000, F=256

#define F 256
#define EPSV 1e-5f

typedef __attribute__((ext_vector_type(8))) short short8;
typedef __attribute__((ext_vector_type(4))) float f32x4;
typedef __attribute__((ext_vector_type(4))) unsigned short us4;

__device__ __forceinline__ unsigned short f2bf(float f) {
  union { float f; unsigned u; } v; v.f = f;
  unsigned r = v.u + 0x7fffu + ((v.u >> 16) & 1u);  // RNE
  return (unsigned short)(r >> 16);
}

__device__ __forceinline__ float bf2f(unsigned short u) {
  union { unsigned u; float f; } v; v.u = ((unsigned)u) << 16; return v.f;
}

// ---- count + rank (edges) ; prep_W (blocks >= eb) --------------------------

__global__ void count_rank(const int* __restrict__ dst, int* __restrict__ deg_cnt,
                           int* __restrict__ rank, int E, int eb,
                           const float* __restrict__ W, unsigned short* __restrict__ Wb) {
  if ((int)blockIdx.x < eb) {
    int e = blockIdx.x * 256 + threadIdx.x;
    if (e < E) rank[e] = atomicAdd(&deg_cnt[dst[e]], 1);
    return;
  }
  int gid = (blockIdx.x - eb) * 256 + threadIdx.x;  // 65536 total
  int j = gid & 7;
  int lane = (gid >> 3) & 63;
  int kc = (gid >> 9) & 7;
  int tt = gid >> 12;
  int k = kc * 32 + (lane >> 4) * 8 + j;
  int n = tt * 16 + (lane & 15);
  Wb[gid] = f2bf(W[k * 256 + n]);
}

// ---- parallel scan chain ---------------------------------------------------

__global__ void block_sums(const int* __restrict__ deg_cnt, int* __restrict__ bsum,
                           float* __restrict__ dinv, int N) {
  __shared__ int s[256];
  int t = threadIdx.x;
  int i = blockIdx.x * 256 + t;
  int d = (i < N) ? deg_cnt[i] : 0;
  if (i < N) dinv[i] = rsqrtf((float)(d + 1));  // +1 self loop
  s[t] = d;
  __syncthreads();
  for (int off = 128; off > 0; off >>= 1) {
    if (t < off) s[t] += s[t + off];
    __syncthreads();
  }
  if (t == 0) bsum[blockIdx.x] = s[0];
}

__global__ void scan_bsums(const int* __restrict__ bsum, int* __restrict__ boff, int nb) {
  __shared__ int s[256];
  int t = threadIdx.x;
  int v = (t < nb) ? bsum[t] : 0;
  s[t] = v;
  __syncthreads();
  for (int off = 1; off < 256; off <<= 1) {
    int x = (t >= off) ? s[t - off] : 0;
    __syncthreads();
    s[t] += x;
    __syncthreads();
  }
  if (t < nb) boff[t] = s[t] - v;  // exclusive
}

__global__ void write_csr(const int* __restrict__ deg_cnt, const int* __restrict__ boff,
                          int* __restrict__ csr_ptr, int N, int E) {
  __shared__ int s[256];
  int t = threadIdx.x;
  int i = blockIdx.x * 256 + t;
  int v = (i < N) ? deg_cnt[i] : 0;
  s[t] = v;
  __syncthreads();
  for (int off = 1; off < 256; off <<= 1) {
    int x = (t >= off) ? s[t - off] : 0;
    __syncthreads();
    s[t] += x;
    __syncthreads();
  }
  if (i < N) csr_ptr[i] = boff[blockIdx.x] + s[t] - v;
  if (i == 0) csr_ptr[N] = E;
}

// ---- fill (atomic-free, blocks < eb) ; gemm (blocks >= eb) -----------------
// gemm writes h' bf16 into slice-major hbs[s][row][8 x us4]

__global__ void fill_gemm(const int* __restrict__ src, const int* __restrict__ dst,
                          const int* __restrict__ rank, const int* __restrict__ csr_ptr,
                          int* __restrict__ csr_src, int E, int eb,
                          const float* __restrict__ x, const unsigned short* __restrict__ Wb,
                          const float* __restrict__ dinv, us4* __restrict__ hbs, int N) {
  __shared__ unsigned short lds[16][264];  // gemm repack; +8 pad breaks bank alias

  if ((int)blockIdx.x < eb) {
    int e = blockIdx.x * 256 + threadIdx.x;
    if (e < E) {
      int d = dst[e];
      csr_src[csr_ptr[d] + rank[e]] = src[e];
    }
    return;
  }

  int bid = blockIdx.x - eb;
  int lane = threadIdx.x & 63;
  int wave = threadIdx.x >> 6;
  int m0 = bid * 16;
  int q = lane >> 4;

  int row = m0 + (lane & 15);
  int rowc = row < N ? row : N - 1;

  f32x4 acc[4] = {{0,0,0,0},{0,0,0,0},{0,0,0,0},{0,0,0,0}};

  for (int kc = 0; kc < 8; ++kc) {
    int koff = kc * 32 + q * 8;
    const float4* xp = (const float4*)(x + (size_t)rowc * F + koff);
    float4 a0 = xp[0];
    float4 a1 = xp[1];
    short8 a;
    a[0] = f2bf(a0.x); a[1] = f2bf(a0.y); a[2] = f2bf(a0.z); a[3] = f2bf(a0.w);
    a[4] = f2bf(a1.x); a[5] = f2bf(a1.y); a[6] = f2bf(a1.z); a[7] = f2bf(a1.w);
#pragma unroll
    for (int tt = 0; tt < 4; ++tt) {
      const short8 b = *(const short8*)(Wb + (((wave * 4 + tt) * 8 + kc) * 64 + lane) * 8);
      acc[tt] = __builtin_amdgcn_mfma_f32_16x16x32_bf16(a, b, acc[tt], 0, 0, 0);
    }
  }

  int crow = q * 4;
  int ccol = lane & 15;
#pragma unroll
  for (int rr = 0; rr < 4; ++rr) {
    int orow = m0 + crow + rr;
    float dv = (orow < N) ? dinv[orow] : 0.f;
#pragma unroll
    for (int tt = 0; tt < 4; ++tt) {
      lds[crow + rr][wave * 64 + tt * 16 + ccol] = f2bf(acc[tt][rr] * dv);
    }
  }
  __syncthreads();
  int t = threadIdx.x;
  int lrow = t >> 4;
  int grow = m0 + lrow;
  if (grow < N) {
#pragma unroll
    for (int it = 0; it < 4; ++it) {
      int c4 = (t & 15) + 16 * it;  // us4 index 0..63 over 256 cols
      us4 u = *(const us4*)&lds[lrow][c4 * 4];
      int sl = c4 >> 3, cc = c4 & 7;
      __builtin_nontemporal_store(u, &hbs[((size_t)sl * N + grow) * 8 + cc]);
    }
  }
}

// ---- Aggregation: slice-per-XCD, thread owns (row, chunk) ------------------
// blockIdx%8 = slice (32 cols, 3.2MB -> one XCD L2). Block = 32 rows x 8 chunks.
// Thread loops its row's edges 8-deep unrolled: 8 independent gathers in flight.

__global__ void aggregate(const us4* __restrict__ hbs, const int* __restrict__ csr_ptr,
                          const int* __restrict__ csr_src, const float* __restrict__ dinv,
                          const float4* __restrict__ conv_bias4, f32x4* __restrict__ out4,
                          float2* __restrict__ partials, int N) {
  int sl = blockIdx.x & 7;
  int rb = blockIdx.x >> 3;
  int t = threadIdx.x;
  int c = t & 7;                 // us4 chunk within slice
  int row = rb * 32 + (t >> 3);
  float ps1 = 0.f, ps2 = 0.f;

  if (row < N) {
    const us4* tab = hbs + (size_t)sl * N * 8;
    int b0 = csr_ptr[row], b1 = csr_ptr[row + 1];
    us4 sv = tab[(size_t)row * 8 + c];  // self loop (h' = h*dinv)
    float ax = bf2f(sv.x), ay = bf2f(sv.y), az = bf2f(sv.z), aw = bf2f(sv.w);

    for (int e = b0; e < b1; e += 8) {
      int idx[8];
#pragma unroll
      for (int j = 0; j < 8; ++j) {
        int ee = e + j;
        idx[j] = __builtin_nontemporal_load(csr_src + (ee < b1 ? ee : b1 - 1));
      }
      us4 v[8];
#pragma unroll
      for (int j = 0; j < 8; ++j) v[j] = tab[(size_t)idx[j] * 8 + c];
#pragma unroll
      for (int j = 0; j < 8; ++j) {
        float m = (e + j < b1) ? 1.f : 0.f;
        ax = fmaf(bf2f(v[j].x), m, ax);
        ay = fmaf(bf2f(v[j].y), m, ay);
        az = fmaf(bf2f(v[j].z), m, az);
        aw = fmaf(bf2f(v[j].w), m, aw);
      }
    }

    float di = dinv[row];
    float4 b = conv_bias4[sl * 8 + c];
    f32x4 y;
    y.x = fmaf(ax, di, b.x);
    y.y = fmaf(ay, di, b.y);
    y.z = fmaf(az, di, b.z);
    y.w = fmaf(aw, di, b.w);
    __builtin_nontemporal_store(y, &out4[(size_t)row * 64 + sl * 8 + c]);
    ps1 = y.x + y.y + y.z + y.w;
    ps2 = y.x * y.x + y.y * y.y + y.z * y.z + y.w * y.w;
  }

  __shared__ float r1[256];
  __shared__ float r2[256];
  r1[t] = ps1;
  r2[t] = ps2;
  __syncthreads();
  for (int off = 128; off > 0; off >>= 1) {
    if (t < off) { r1[t] += r1[t + off]; r2[t] += r2[t + off]; }
    __syncthreads();
  }
  if (t == 0) {
    float2 pp;
    pp.x = r1[0];
    pp.y = r2[0];
    partials[blockIdx.x] = pp;
  }
}

__global__ void finalize_stats(const float2* __restrict__ partials, int nb,
                               float* __restrict__ stats, double cnt) {
  __shared__ double q1[1024];
  __shared__ double q2[1024];
  int t = threadIdx.x;
  double a1 = 0.0, a2 = 0.0;
  for (int i = t; i < nb; i += 1024) {
    float2 pp = partials[i];
    a1 += (double)pp.x;
    a2 += (double)pp.y;
  }
  q1[t] = a1;
  q2[t] = a2;
  __syncthreads();
  for (int off = 512; off > 0; off >>= 1) {
    if (t < off) { q1[t] += q1[t + off]; q2[t] += q2[t + off]; }
    __syncthreads();
  }
  if (t == 0) {
    double mu = q1[0] / cnt;
    double var = q2[0] / cnt - mu * mu;
    if (var < 0) var = 0;
    double sd = sqrt(var);
    stats[0] = (float)mu;
    stats[1] = (float)(1.0 / (sd + (double)EPSV));
  }
}

__global__ void norm_prelu(float4* __restrict__ out, const float* __restrict__ stats,
                           const float* __restrict__ lw, const float* __restrict__ lb,
                           const float* __restrict__ pa, int n4) {
  int i = blockIdx.x * blockDim.x + threadIdx.x;
  if (i >= n4) return;
  float mu = stats[0];
  float inv = stats[1];
  float a = pa[0];
  int c4 = (i & 63) * 4;
  float4 w = *(const float4*)(lw + c4);
  float4 b = *(const float4*)(lb + c4);
  float4 v = out[i];
  float y0 = (v.x - mu) * inv * w.x + b.x;
  float y1 = (v.y - mu) * inv * w.y + b.y;
  float y2 = (v.z - mu) * inv * w.z + b.z;
  float y3 = (v.w - mu) * inv * w.w + b.w;
  v.x = y0 >= 0.f ? y0 : a * y0;
  v.y = y1 >= 0.f ? y1 : a * y1;
  v.z = y2 >= 0.f ? y2 : a * y2;
  v.w = y3 >= 0.f ? y3 : a * y3;
  out[i] = v;
}

// ---- launch ---------------------------------------------------------------

extern "C" void kernel_launch(void* const* d_in, const int* in_sizes, int n_in,
                              void* d_out, int out_size, void* d_ws, size_t ws_size,
                              hipStream_t stream) {
  const float* x = (const float*)d_in[0];
  const int* eidx = (const int*)d_in[1];
  const float* W = (const float*)d_in[3];
  const float* conv_bias = (const float*)d_in[4];
  const float* ln_w = (const float*)d_in[5];
  const float* ln_b = (const float*)d_in[6];
  const float* prelu_a = (const float*)d_in[7];
  float* out = (float*)d_out;

  int N = in_sizes[0] / F;
  int E = in_sizes[1] / 2;
  const int* src = eidx;
  const int* dst = eidx + E;

  int rowBlocks = (N + 31) / 32;
  int nAggBlocks = rowBlocks * 8;
  int eb = (E + 255) / 256;
  int gemmb = (N + 15) / 16;
  int NB = (N + 255) / 256;

  char* p = (char*)d_ws;
  auto carve = [&](size_t bytes) { char* r = p; p += (bytes + 255) & ~(size_t)255; return r; };
  us4* hbs       = (us4*)carve((size_t)N * 64 * sizeof(us4));  // sliced bf16 h'
  unsigned short* Wb = (unsigned short*)carve((size_t)F * F * sizeof(short));
  int* deg_cnt   = (int*)carve((size_t)N * sizeof(int));
  int* rank      = (int*)carve((size_t)E * sizeof(int));
  float* dinv    = (float*)carve((size_t)N * sizeof(float));
  int* csr_ptr   = (int*)carve((size_t)(N + 1) * sizeof(int));
  int* csr_src   = (int*)carve((size_t)E * sizeof(int));
  int* bsum      = (int*)carve((size_t)NB * sizeof(int));
  int* boff      = (int*)carve((size_t)NB * sizeof(int));
  float2* partials = (float2*)carve((size_t)nAggBlocks * sizeof(float2));
  float* stats   = (float*)carve(2 * sizeof(float));

  hipMemsetAsync(deg_cnt, 0, (size_t)N * sizeof(int), stream);

  count_rank<<<eb + 256, 256, 0, stream>>>(dst, deg_cnt, rank, E, eb, W, Wb);
  block_sums<<<NB, 256, 0, stream>>>(deg_cnt, bsum, dinv, N);
  scan_bsums<<<1, 256, 0, stream>>>(bsum, boff, NB);
  write_csr<<<NB, 256, 0, stream>>>(deg_cnt, boff, csr_ptr, N, E);
  fill_gemm<<<eb + gemmb, 256, 0, stream>>>(src, dst, rank, csr_ptr, csr_src, E, eb,
                                            x, Wb, dinv, hbs, N);
  aggregate<<<nAggBlocks, 256, 0, stream>>>(hbs, csr_ptr, csr_src, dinv,
                                            (const float4*)conv_bias, (f32x4*)out,
                                            partials, N);
  finalize_stats<<<1, 1024, 0, stream>>>(partials, nAggBlocks, stats,
                                         (double)N * (double)F);
  int n4 = N * (F / 4);
  norm_prelu<<<(n4 + 255) / 256, 256, 0, stream>>>((float4*)out, stats, ln_w, ln_b, prelu_a, n4);
}

// Round 10
// 324.993 us; speedup vs baseline: 1.3099x; 1.0266x over previous
//
#include <hip/hip_runtime.h>
#include <hip/hip_bf16.h>

// GCNBlock: 9-dispatch pipeline; h' bf16 column-sliced (8 x 3.2MB) for per-XCD
// L2-resident gathers; aggregation: thread owns (row, 16B chunk), us8 loads.
// N=50000, E=800000, F=256

#define F 256
#define EPSV 1e-5f

typedef __attribute__((ext_vector_type(8))) short short8;
typedef __attribute__((ext_vector_type(4))) float f32x4;
typedef __attribute__((ext_vector_type(4))) unsigned short us4;
typedef __attribute__((ext_vector_type(8))) unsigned short us8;

__device__ __forceinline__ unsigned short f2bf(float f) {
  union { float f; unsigned u; } v; v.f = f;
  unsigned r = v.u + 0x7fffu + ((v.u >> 16) & 1u);  // RNE
  return (unsigned short)(r >> 16);
}

__device__ __forceinline__ float bf2f(unsigned short u) {
  union { unsigned u; float f; } v; v.u = ((unsigned)u) << 16; return v.f;
}

// ---- count + rank (edges) ; prep_W (blocks >= eb) --------------------------

__global__ void count_rank(const int* __restrict__ dst, int* __restrict__ deg_cnt,
                           int* __restrict__ rank, int E, int eb,
                           const float* __restrict__ W, unsigned short* __restrict__ Wb) {
  if ((int)blockIdx.x < eb) {
    int e = blockIdx.x * 256 + threadIdx.x;
    if (e < E) rank[e] = atomicAdd(&deg_cnt[dst[e]], 1);
    return;
  }
  int gid = (blockIdx.x - eb) * 256 + threadIdx.x;  // 65536 total
  int j = gid & 7;
  int lane = (gid >> 3) & 63;
  int kc = (gid >> 9) & 7;
  int tt = gid >> 12;
  int k = kc * 32 + (lane >> 4) * 8 + j;
  int n = tt * 16 + (lane & 15);
  Wb[gid] = f2bf(W[k * 256 + n]);
}

// ---- parallel scan chain ---------------------------------------------------

__global__ void block_sums(const int* __restrict__ deg_cnt, int* __restrict__ bsum,
                           float* __restrict__ dinv, int N) {
  __shared__ int s[256];
  int t = threadIdx.x;
  int i = blockIdx.x * 256 + t;
  int d = (i < N) ? deg_cnt[i] : 0;
  if (i < N) dinv[i] = rsqrtf((float)(d + 1));  // +1 self loop
  s[t] = d;
  __syncthreads();
  for (int off = 128; off > 0; off >>= 1) {
    if (t < off) s[t] += s[t + off];
    __syncthreads();
  }
  if (t == 0) bsum[blockIdx.x] = s[0];
}

__global__ void scan_bsums(const int* __restrict__ bsum, int* __restrict__ boff, int nb) {
  __shared__ int s[256];
  int t = threadIdx.x;
  int v = (t < nb) ? bsum[t] : 0;
  s[t] = v;
  __syncthreads();
  for (int off = 1; off < 256; off <<= 1) {
    int x = (t >= off) ? s[t - off] : 0;
    __syncthreads();
    s[t] += x;
    __syncthreads();
  }
  if (t < nb) boff[t] = s[t] - v;  // exclusive
}

__global__ void write_csr(const int* __restrict__ deg_cnt, const int* __restrict__ boff,
                          int* __restrict__ csr_ptr, int N, int E) {
  __shared__ int s[256];
  int t = threadIdx.x;
  int i = blockIdx.x * 256 + t;
  int v = (i < N) ? deg_cnt[i] : 0;
  s[t] = v;
  __syncthreads();
  for (int off = 1; off < 256; off <<= 1) {
    int x = (t >= off) ? s[t - off] : 0;
    __syncthreads();
    s[t] += x;
    __syncthreads();
  }
  if (i < N) csr_ptr[i] = boff[blockIdx.x] + s[t] - v;
  if (i == 0) csr_ptr[N] = E;
}

// ---- fill (atomic-free, blocks < eb) ; gemm (blocks >= eb) -----------------
// gemm writes h' bf16 into slice-major hbs[s][row][8 x us4]

__global__ void fill_gemm(const int* __restrict__ src, const int* __restrict__ dst,
                          const int* __restrict__ rank, const int* __restrict__ csr_ptr,
                          int* __restrict__ csr_src, int E, int eb,
                          const float* __restrict__ x, const unsigned short* __restrict__ Wb,
                          const float* __restrict__ dinv, us4* __restrict__ hbs, int N) {
  __shared__ unsigned short lds[16][264];  // gemm repack; +8 pad breaks bank alias

  if ((int)blockIdx.x < eb) {
    int e = blockIdx.x * 256 + threadIdx.x;
    if (e < E) {
      int d = dst[e];
      csr_src[csr_ptr[d] + rank[e]] = src[e];
    }
    return;
  }

  int bid = blockIdx.x - eb;
  int lane = threadIdx.x & 63;
  int wave = threadIdx.x >> 6;
  int m0 = bid * 16;
  int q = lane >> 4;

  int row = m0 + (lane & 15);
  int rowc = row < N ? row : N - 1;

  f32x4 acc[4] = {{0,0,0,0},{0,0,0,0},{0,0,0,0},{0,0,0,0}};

  for (int kc = 0; kc < 8; ++kc) {
    int koff = kc * 32 + q * 8;
    const float4* xp = (const float4*)(x + (size_t)rowc * F + koff);
    float4 a0 = xp[0];
    float4 a1 = xp[1];
    short8 a;
    a[0] = f2bf(a0.x); a[1] = f2bf(a0.y); a[2] = f2bf(a0.z); a[3] = f2bf(a0.w);
    a[4] = f2bf(a1.x); a[5] = f2bf(a1.y); a[6] = f2bf(a1.z); a[7] = f2bf(a1.w);
#pragma unroll
    for (int tt = 0; tt < 4; ++tt) {
      const short8 b = *(const short8*)(Wb + (((wave * 4 + tt) * 8 + kc) * 64 + lane) * 8);
      acc[tt] = __builtin_amdgcn_mfma_f32_16x16x32_bf16(a, b, acc[tt], 0, 0, 0);
    }
  }

  int crow = q * 4;
  int ccol = lane & 15;
#pragma unroll
  for (int rr = 0; rr < 4; ++rr) {
    int orow = m0 + crow + rr;
    float dv = (orow < N) ? dinv[orow] : 0.f;
#pragma unroll
    for (int tt = 0; tt < 4; ++tt) {
      lds[crow + rr][wave * 64 + tt * 16 + ccol] = f2bf(acc[tt][rr] * dv);
    }
  }
  __syncthreads();
  int t = threadIdx.x;
  int lrow = t >> 4;
  int grow = m0 + lrow;
  if (grow < N) {
#pragma unroll
    for (int it = 0; it < 4; ++it) {
      int c4 = (t & 15) + 16 * it;  // us4 index 0..63 over 256 cols
      us4 u = *(const us4*)&lds[lrow][c4 * 4];
      int sl = c4 >> 3, cc = c4 & 7;
      __builtin_nontemporal_store(u, &hbs[((size_t)sl * N + grow) * 8 + cc]);
    }
  }
}

// ---- Aggregation: slice-per-XCD, thread owns (row, 16B chunk) --------------
// blockIdx%8 = slice (32 cols, 3.2MB -> one XCD L2). Block = 64 rows x 4 chunks.
// Per edge: 4 us8 (16B) lane-loads instead of 8 us4 -> half the gather instrs.

__global__ void aggregate(const us8* __restrict__ hbs8, const int* __restrict__ csr_ptr,
                          const int* __restrict__ csr_src, const float* __restrict__ dinv,
                          const f32x4* __restrict__ conv_bias4, f32x4* __restrict__ out4,
                          float2* __restrict__ partials, int N) {
  int sl = blockIdx.x & 7;
  int rb = blockIdx.x >> 3;
  int t = threadIdx.x;
  int c = t & 3;                 // us8 (16B) chunk within 64B slice row
  int row = rb * 64 + (t >> 2);
  float ps1 = 0.f, ps2 = 0.f;

  if (row < N) {
    const us8* tab = hbs8 + (size_t)sl * N * 4;
    int b0 = csr_ptr[row], b1 = csr_ptr[row + 1];
    us8 sv = tab[(size_t)row * 4 + c];  // self loop (h' = h*dinv)
    float a0 = bf2f(sv[0]), a1 = bf2f(sv[1]), a2 = bf2f(sv[2]), a3 = bf2f(sv[3]);
    float a4 = bf2f(sv[4]), a5 = bf2f(sv[5]), a6 = bf2f(sv[6]), a7 = bf2f(sv[7]);

    for (int e = b0; e < b1; e += 8) {
      int idx[8];
#pragma unroll
      for (int j = 0; j < 8; ++j) {
        int ee = e + j;
        idx[j] = __builtin_nontemporal_load(csr_src + (ee < b1 ? ee : b1 - 1));
      }
      us8 v[8];
#pragma unroll
      for (int j = 0; j < 8; ++j) v[j] = tab[(size_t)idx[j] * 4 + c];
#pragma unroll
      for (int j = 0; j < 8; ++j) {
        float m = (e + j < b1) ? 1.f : 0.f;
        a0 = fmaf(bf2f(v[j][0]), m, a0);
        a1 = fmaf(bf2f(v[j][1]), m, a1);
        a2 = fmaf(bf2f(v[j][2]), m, a2);
        a3 = fmaf(bf2f(v[j][3]), m, a3);
        a4 = fmaf(bf2f(v[j][4]), m, a4);
        a5 = fmaf(bf2f(v[j][5]), m, a5);
        a6 = fmaf(bf2f(v[j][6]), m, a6);
        a7 = fmaf(bf2f(v[j][7]), m, a7);
      }
    }

    float di = dinv[row];
    int cb = sl * 8 + c * 2;  // float4 index into bias / out row
    f32x4 bA = conv_bias4[cb];
    f32x4 bB = conv_bias4[cb + 1];
    f32x4 yA, yB;
    yA.x = fmaf(a0, di, bA.x);
    yA.y = fmaf(a1, di, bA.y);
    yA.z = fmaf(a2, di, bA.z);
    yA.w = fmaf(a3, di, bA.w);
    yB.x = fmaf(a4, di, bB.x);
    yB.y = fmaf(a5, di, bB.y);
    yB.z = fmaf(a6, di, bB.z);
    yB.w = fmaf(a7, di, bB.w);
    __builtin_nontemporal_store(yA, &out4[(size_t)row * 64 + cb]);
    __builtin_nontemporal_store(yB, &out4[(size_t)row * 64 + cb + 1]);
    ps1 = yA.x + yA.y + yA.z + yA.w + yB.x + yB.y + yB.z + yB.w;
    ps2 = yA.x * yA.x + yA.y * yA.y + yA.z * yA.z + yA.w * yA.w +
          yB.x * yB.x + yB.y * yB.y + yB.z * yB.z + yB.w * yB.w;
  }

  __shared__ float r1[256];
  __shared__ float r2[256];
  r1[t] = ps1;
  r2[t] = ps2;
  __syncthreads();
  for (int off = 128; off > 0; off >>= 1) {
    if (t < off) { r1[t] += r1[t + off]; r2[t] += r2[t + off]; }
    __syncthreads();
  }
  if (t == 0) {
    float2 pp;
    pp.x = r1[0];
    pp.y = r2[0];
    partials[blockIdx.x] = pp;
  }
}

__global__ void finalize_stats(const float2* __restrict__ partials, int nb,
                               float* __restrict__ stats, double cnt) {
  __shared__ double q1[1024];
  __shared__ double q2[1024];
  int t = threadIdx.x;
  double a1 = 0.0, a2 = 0.0;
  for (int i = t; i < nb; i += 1024) {
    float2 pp = partials[i];
    a1 += (double)pp.x;
    a2 += (double)pp.y;
  }
  q1[t] = a1;
  q2[t] = a2;
  __syncthreads();
  for (int off = 512; off > 0; off >>= 1) {
    if (t < off) { q1[t] += q1[t + off]; q2[t] += q2[t + off]; }
    __syncthreads();
  }
  if (t == 0) {
    double mu = q1[0] / cnt;
    double var = q2[0] / cnt - mu * mu;
    if (var < 0) var = 0;
    double sd = sqrt(var);
    stats[0] = (float)mu;
    stats[1] = (float)(1.0 / (sd + (double)EPSV));
  }
}

__global__ void norm_prelu(float4* __restrict__ out, const float* __restrict__ stats,
                           const float* __restrict__ lw, const float* __restrict__ lb,
                           const float* __restrict__ pa, int n4) {
  int i = blockIdx.x * blockDim.x + threadIdx.x;
  if (i >= n4) return;
  float mu = stats[0];
  float inv = stats[1];
  float a = pa[0];
  int c4 = (i & 63) * 4;
  float4 w = *(const float4*)(lw + c4);
  float4 b = *(const float4*)(lb + c4);
  float4 v = out[i];
  float y0 = (v.x - mu) * inv * w.x + b.x;
  float y1 = (v.y - mu) * inv * w.y + b.y;
  float y2 = (v.z - mu) * inv * w.z + b.z;
  float y3 = (v.w - mu) * inv * w.w + b.w;
  v.x = y0 >= 0.f ? y0 : a * y0;
  v.y = y1 >= 0.f ? y1 : a * y1;
  v.z = y2 >= 0.f ? y2 : a * y2;
  v.w = y3 >= 0.f ? y3 : a * y3;
  out[i] = v;
}

// ---- launch ---------------------------------------------------------------

extern "C" void kernel_launch(void* const* d_in, const int* in_sizes, int n_in,
                              void* d_out, int out_size, void* d_ws, size_t ws_size,
                              hipStream_t stream) {
  const float* x = (const float*)d_in[0];
  const int* eidx = (const int*)d_in[1];
  const float* W = (const float*)d_in[3];
  const float* conv_bias = (const float*)d_in[4];
  const float* ln_w = (const float*)d_in[5];
  const float* ln_b = (const float*)d_in[6];
  const float* prelu_a = (const float*)d_in[7];
  float* out = (float*)d_out;

  int N = in_sizes[0] / F;
  int E = in_sizes[1] / 2;
  const int* src = eidx;
  const int* dst = eidx + E;

  int rowBlocks = (N + 63) / 64;
  int nAggBlocks = rowBlocks * 8;
  int eb = (E + 255) / 256;
  int gemmb = (N + 15) / 16;
  int NB = (N + 255) / 256;

  char* p = (char*)d_ws;
  auto carve = [&](size_t bytes) { char* r = p; p += (bytes + 255) & ~(size_t)255; return r; };
  us4* hbs       = (us4*)carve((size_t)N * 64 * sizeof(us4));  // sliced bf16 h'
  unsigned short* Wb = (unsigned short*)carve((size_t)F * F * sizeof(short));
  int* deg_cnt   = (int*)carve((size_t)N * sizeof(int));
  int* rank      = (int*)carve((size_t)E * sizeof(int));
  float* dinv    = (float*)carve((size_t)N * sizeof(float));
  int* csr_ptr   = (int*)carve((size_t)(N + 1) * sizeof(int));
  int* csr_src   = (int*)carve((size_t)E * sizeof(int));
  int* bsum      = (int*)carve((size_t)NB * sizeof(int));
  int* boff      = (int*)carve((size_t)NB * sizeof(int));
  float2* partials = (float2*)carve((size_t)nAggBlocks * sizeof(float2));
  float* stats   = (float*)carve(2 * sizeof(float));

  hipMemsetAsync(deg_cnt, 0, (size_t)N * sizeof(int), stream);

  count_rank<<<eb + 256, 256, 0, stream>>>(dst, deg_cnt, rank, E, eb, W, Wb);
  block_sums<<<NB, 256, 0, stream>>>(deg_cnt, bsum, dinv, N);
  scan_bsums<<<1, 256, 0, stream>>>(bsum, boff, NB);
  write_csr<<<NB, 256, 0, stream>>>(deg_cnt, boff, csr_ptr, N, E);
  fill_gemm<<<eb + gemmb, 256, 0, stream>>>(src, dst, rank, csr_ptr, csr_src, E, eb,
                                            x, Wb, dinv, hbs, N);
  aggregate<<<nAggBlocks, 256, 0, stream>>>((const us8*)hbs, csr_ptr, csr_src, dinv,
                                            (const f32x4*)conv_bias, (f32x4*)out,
                                            partials, N);
  finalize_stats<<<1, 1024, 0, stream>>>(partials, nAggBlocks, stats,
                                         (double)N * (double)F);
  int n4 = N * (F / 4);
  norm_prelu<<<(n4 + 255) / 256, 256, 0, stream>>>((float4*)out, stats, ln_w, ln_b, prelu_a, n4);
}